// Round 1
// baseline (158.334 us; speedup 1.0000x reference)
//
#include <hip/hip_runtime.h>

#define GNX 96
#define GNY 96
#define GNZ 96

__global__ __launch_bounds__(256) void bspline_ffd_kernel(
    const float* __restrict__ verts,
    const float* __restrict__ dG,
    const float* __restrict__ origin,
    const float* __restrict__ spacing,
    float* __restrict__ out,
    int n)
{
    int i = blockIdx.x * blockDim.x + threadIdx.x;
    if (i >= n) return;

    float vx = verts[3 * i + 0];
    float vy = verts[3 * i + 1];
    float vz = verts[3 * i + 2];

    // origin/spacing are wave-uniform -> compiler emits scalar loads
    float rel[3];
    rel[0] = (vx - origin[0]) / spacing[0];
    rel[1] = (vy - origin[1]) / spacing[1];
    rel[2] = (vz - origin[2]) / spacing[2];

    const int dims[3] = {GNX, GNY, GNZ};
    float B[3][4];
    int   idx[3][4];

    #pragma unroll
    for (int d = 0; d < 3; ++d) {
        float b  = floorf(rel[d]);
        float u  = rel[d] - b;
        u = fminf(fmaxf(u, 0.0f), 1.0f);
        float u2 = u * u;
        float u3 = u2 * u;
        float bb[4];
        bb[0] = (1.0f - 3.0f * u + 3.0f * u2 - u3) * (1.0f / 6.0f);
        bb[1] = (4.0f - 6.0f * u2 + 3.0f * u3) * (1.0f / 6.0f);
        bb[2] = (1.0f + 3.0f * u + 3.0f * u2 - 3.0f * u3) * (1.0f / 6.0f);
        bb[3] = u3 * (1.0f / 6.0f);
        int ib = (int)b - 1;
        #pragma unroll
        for (int j = 0; j < 4; ++j) {
            int  id    = ib + j;
            bool valid = (id >= 0) && (id < dims[d]);
            B[d][j]   = valid ? bb[j] : 0.0f;   // zero weight == reference mask
            idx[d][j] = valid ? id    : 0;      // clamped index, never OOB
        }
    }

    float acc0 = 0.0f, acc1 = 0.0f, acc2 = 0.0f;

    #pragma unroll
    for (int a = 0; a < 4; ++a) {
        float Ba  = B[0][a];
        int   ia  = idx[0][a] * GNY;
        float sa0 = 0.0f, sa1 = 0.0f, sa2 = 0.0f;
        #pragma unroll
        for (int b = 0; b < 4; ++b) {
            float Bb  = B[1][b];
            int   ibb = (ia + idx[1][b]) * GNZ;
            float sb0 = 0.0f, sb1 = 0.0f, sb2 = 0.0f;
            #pragma unroll
            for (int c = 0; c < 4; ++c) {
                float Bc = B[2][c];
                const float* p = dG + 3 * (ibb + idx[2][c]);
                sb0 = fmaf(Bc, p[0], sb0);
                sb1 = fmaf(Bc, p[1], sb1);
                sb2 = fmaf(Bc, p[2], sb2);
            }
            sa0 = fmaf(Bb, sb0, sa0);
            sa1 = fmaf(Bb, sb1, sa1);
            sa2 = fmaf(Bb, sb2, sa2);
        }
        acc0 = fmaf(Ba, sa0, acc0);
        acc1 = fmaf(Ba, sa1, acc1);
        acc2 = fmaf(Ba, sa2, acc2);
    }

    out[3 * i + 0] = vx + acc0;
    out[3 * i + 1] = vy + acc1;
    out[3 * i + 2] = vz + acc2;
}

extern "C" void kernel_launch(void* const* d_in, const int* in_sizes, int n_in,
                              void* d_out, int out_size, void* d_ws, size_t ws_size,
                              hipStream_t stream) {
    const float* verts   = (const float*)d_in[0];
    const float* dG      = (const float*)d_in[1];
    const float* origin  = (const float*)d_in[2];
    const float* spacing = (const float*)d_in[3];
    float* out = (float*)d_out;

    int n = in_sizes[0] / 3;  // 500000 vertices
    int block = 256;
    int grid  = (n + block - 1) / block;
    bspline_ffd_kernel<<<grid, block, 0, stream>>>(verts, dG, origin, spacing, out, n);
}

// Round 2
// 114.777 us; speedup vs baseline: 1.3795x; 1.3795x over previous
//
#include <hip/hip_runtime.h>

#define GNX 96
#define GNY 96
#define GNZ 96
#define BSHIFT 2                 // bin = cell >> 2 -> 24 bins per dim (4^3 cells per bin)
#define NBDIM 24
#define NBINS (NBDIM * NBDIM * NBDIM)   // 13824
#define NXCD 8

// ---------------- shared per-vertex FFD math ----------------
__device__ __forceinline__ void ffd_compute(
    float vx, float vy, float vz,
    const float* __restrict__ dG,
    const float* __restrict__ origin,
    const float* __restrict__ spacing,
    float res[3])
{
    float rel[3];
    rel[0] = (vx - origin[0]) / spacing[0];
    rel[1] = (vy - origin[1]) / spacing[1];
    rel[2] = (vz - origin[2]) / spacing[2];

    const int dims[3] = {GNX, GNY, GNZ};
    float B[3][4];
    int   idx[3][4];

    #pragma unroll
    for (int d = 0; d < 3; ++d) {
        float b  = floorf(rel[d]);
        float u  = rel[d] - b;
        u = fminf(fmaxf(u, 0.0f), 1.0f);
        float u2 = u * u;
        float u3 = u2 * u;
        float bb[4];
        bb[0] = (1.0f - 3.0f * u + 3.0f * u2 - u3) * (1.0f / 6.0f);
        bb[1] = (4.0f - 6.0f * u2 + 3.0f * u3) * (1.0f / 6.0f);
        bb[2] = (1.0f + 3.0f * u + 3.0f * u2 - 3.0f * u3) * (1.0f / 6.0f);
        bb[3] = u3 * (1.0f / 6.0f);
        int ib = (int)b - 1;
        #pragma unroll
        for (int j = 0; j < 4; ++j) {
            int  id    = ib + j;
            bool valid = (id >= 0) && (id < dims[d]);
            B[d][j]   = valid ? bb[j] : 0.0f;   // zero weight == reference mask
            idx[d][j] = valid ? id    : 0;      // clamped index, never OOB
        }
    }

    float acc0 = 0.0f, acc1 = 0.0f, acc2 = 0.0f;
    #pragma unroll
    for (int a = 0; a < 4; ++a) {
        float Ba  = B[0][a];
        int   ia  = idx[0][a] * GNY;
        float sa0 = 0.0f, sa1 = 0.0f, sa2 = 0.0f;
        #pragma unroll
        for (int b = 0; b < 4; ++b) {
            float Bb  = B[1][b];
            int   ibb = (ia + idx[1][b]) * GNZ;
            float sb0 = 0.0f, sb1 = 0.0f, sb2 = 0.0f;
            #pragma unroll
            for (int c = 0; c < 4; ++c) {
                float Bc = B[2][c];
                const float* p = dG + 3 * (ibb + idx[2][c]);
                sb0 = fmaf(Bc, p[0], sb0);
                sb1 = fmaf(Bc, p[1], sb1);
                sb2 = fmaf(Bc, p[2], sb2);
            }
            sa0 = fmaf(Bb, sb0, sa0);
            sa1 = fmaf(Bb, sb1, sa1);
            sa2 = fmaf(Bb, sb2, sa2);
        }
        acc0 = fmaf(Ba, sa0, acc0);
        acc1 = fmaf(Ba, sa1, acc1);
        acc2 = fmaf(Ba, sa2, acc2);
    }
    res[0] = vx + acc0;
    res[1] = vy + acc1;
    res[2] = vz + acc2;
}

__device__ __forceinline__ int bin_of(float v, float o, float sp, int dim) {
    float rel = (v - o) / sp;
    int b = (int)floorf(rel);
    b = min(max(b, 0), dim - 1);
    return b >> BSHIFT;
}

// ---------------- pass 1: histogram ----------------
__global__ __launch_bounds__(256) void hist_kernel(
    const float* __restrict__ verts,
    const float* __restrict__ origin,
    const float* __restrict__ spacing,
    unsigned* __restrict__ hist, int n)
{
    int i = blockIdx.x * 256 + threadIdx.x;
    if (i >= n) return;
    int bx = bin_of(verts[3 * i + 0], origin[0], spacing[0], GNX);
    int by = bin_of(verts[3 * i + 1], origin[1], spacing[1], GNY);
    int bz = bin_of(verts[3 * i + 2], origin[2], spacing[2], GNZ);
    int bin = (bx * NBDIM + by) * NBDIM + bz;
    atomicAdd(&hist[bin], 1u);
}

// ---------------- pass 2: exclusive scan over NBINS (single block) ----------------
__global__ __launch_bounds__(1024) void scan_kernel(unsigned* __restrict__ hist)
{
    __shared__ unsigned part[1024];
    const int IT = (NBINS + 1023) / 1024;  // 14
    int t = threadIdx.x;
    int base = t * IT;
    unsigned vals[14];
    unsigned s = 0;
    #pragma unroll
    for (int j = 0; j < IT; ++j) {
        int b = base + j;
        unsigned v = (b < NBINS) ? hist[b] : 0u;
        vals[j] = s;          // local exclusive prefix
        s += v;
    }
    part[t] = s;
    __syncthreads();
    for (int off = 1; off < 1024; off <<= 1) {
        unsigned x = 0;
        if (t >= off) x = part[t - off];
        __syncthreads();
        if (t >= off) part[t] += x;
        __syncthreads();
    }
    unsigned ex = (t == 0) ? 0u : part[t - 1];
    #pragma unroll
    for (int j = 0; j < IT; ++j) {
        int b = base + j;
        if (b < NBINS) hist[b] = ex + vals[j];
    }
}

// ---------------- pass 3: scatter into sorted order ----------------
__global__ __launch_bounds__(256) void scatter_kernel(
    const float* __restrict__ verts,
    const float* __restrict__ origin,
    const float* __restrict__ spacing,
    unsigned* __restrict__ offs,
    uint4* __restrict__ sorted, int n)
{
    int i = blockIdx.x * 256 + threadIdx.x;
    if (i >= n) return;
    float vx = verts[3 * i + 0];
    float vy = verts[3 * i + 1];
    float vz = verts[3 * i + 2];
    int bx = bin_of(vx, origin[0], spacing[0], GNX);
    int by = bin_of(vy, origin[1], spacing[1], GNY);
    int bz = bin_of(vz, origin[2], spacing[2], GNZ);
    int bin = (bx * NBDIM + by) * NBDIM + bz;
    unsigned pos = atomicAdd(&offs[bin], 1u);
    uint4 rec;
    rec.x = __float_as_uint(vx);
    rec.y = __float_as_uint(vy);
    rec.z = __float_as_uint(vz);
    rec.w = (unsigned)i;
    sorted[pos] = rec;
}

// ---------------- pass 4: main FFD over sorted verts ----------------
__global__ __launch_bounds__(256) void ffd_sorted_kernel(
    const uint4* __restrict__ sorted,
    const float* __restrict__ dG,
    const float* __restrict__ origin,
    const float* __restrict__ spacing,
    float* __restrict__ out, int n, int nwg)
{
    // bijective chunked XCD swizzle: blocks resident on the same XCD get a
    // contiguous range of sorted vertices -> per-XCD L2 holds one slab of dG
    int b = blockIdx.x;
    int q = nwg / NXCD, r = nwg % NXCD;
    int xcd = b % NXCD, pos = b / NXCD;
    int start = (xcd < r) ? xcd * (q + 1) : r * (q + 1) + (xcd - r) * q;
    int blk = start + pos;

    int i = blk * 256 + threadIdx.x;
    if (i >= n) return;

    uint4 rec = sorted[i];
    float vx = __uint_as_float(rec.x);
    float vy = __uint_as_float(rec.y);
    float vz = __uint_as_float(rec.z);
    unsigned orig = rec.w;

    float res[3];
    ffd_compute(vx, vy, vz, dG, origin, spacing, res);

    out[3 * orig + 0] = res[0];
    out[3 * orig + 1] = res[1];
    out[3 * orig + 2] = res[2];
}

// ---------------- fallback: direct (unsorted) ----------------
__global__ __launch_bounds__(256) void ffd_direct_kernel(
    const float* __restrict__ verts,
    const float* __restrict__ dG,
    const float* __restrict__ origin,
    const float* __restrict__ spacing,
    float* __restrict__ out, int n)
{
    int i = blockIdx.x * 256 + threadIdx.x;
    if (i >= n) return;
    float res[3];
    ffd_compute(verts[3 * i], verts[3 * i + 1], verts[3 * i + 2],
                dG, origin, spacing, res);
    out[3 * i + 0] = res[0];
    out[3 * i + 1] = res[1];
    out[3 * i + 2] = res[2];
}

extern "C" void kernel_launch(void* const* d_in, const int* in_sizes, int n_in,
                              void* d_out, int out_size, void* d_ws, size_t ws_size,
                              hipStream_t stream) {
    const float* verts   = (const float*)d_in[0];
    const float* dG      = (const float*)d_in[1];
    const float* origin  = (const float*)d_in[2];
    const float* spacing = (const float*)d_in[3];
    float* out = (float*)d_out;

    int n = in_sizes[0] / 3;              // 500000 vertices
    int nblk = (n + 255) / 256;

    size_t histBytes   = (size_t)NBINS * sizeof(unsigned);     // 55296
    size_t sortedBytes = (size_t)n * sizeof(uint4);            // 8 MB
    size_t need = histBytes + sortedBytes;

    if (ws_size < need) {
        // not enough scratch: correct but slower path
        ffd_direct_kernel<<<nblk, 256, 0, stream>>>(verts, dG, origin, spacing, out, n);
        return;
    }

    unsigned* hist  = (unsigned*)d_ws;
    uint4*  sorted  = (uint4*)((char*)d_ws + histBytes);

    hipMemsetAsync(hist, 0, histBytes, stream);
    hist_kernel<<<nblk, 256, 0, stream>>>(verts, origin, spacing, hist, n);
    scan_kernel<<<1, 1024, 0, stream>>>(hist);
    scatter_kernel<<<nblk, 256, 0, stream>>>(verts, origin, spacing, hist, sorted, n);
    ffd_sorted_kernel<<<nblk, 256, 0, stream>>>(sorted, dG, origin, spacing, out, n, nblk);
}